// Round 5
// baseline (405.132 us; speedup 1.0000x reference)
//
#include <hip/hip_runtime.h>
#include <hip/hip_bf16.h>
#include <cstdint>
#include <cstddef>

// B=2, S=2048, D=512, H=8, DK=64
#define BB 2
#define SS 2048
#define DD 512
#define HH 8
#define DKK 64

typedef __attribute__((ext_vector_type(8))) short bf16x8;   // 8 bf16 = 4 VGPRs
typedef __attribute__((ext_vector_type(4))) float f32x4;

__device__ __forceinline__ unsigned short f2bf(float f) {
    union { float f; unsigned u; } v; v.f = f;
    unsigned u = v.u;
    return (unsigned short)((u + 0x7fffu + ((u >> 16) & 1u)) >> 16);   // RNE
}
__device__ __forceinline__ unsigned pack2(float a, float b) {
    return (unsigned)f2bf(a) | ((unsigned)f2bf(b) << 16);
}

typedef const __attribute__((address_space(1))) unsigned int* gp_t;
typedef __attribute__((address_space(3))) unsigned int* lp_t;
__device__ __forceinline__ void gload_lds16(const void* g, void* l) {
    __builtin_amdgcn_global_load_lds((gp_t)g, (lp_t)l, 16, 0, 0);
}

#define VM_WAIT4 asm volatile("s_waitcnt vmcnt(4)" ::: "memory")
#define VM_WAIT0 asm volatile("s_waitcnt vmcnt(0)" ::: "memory")

// ---------------------------------------------------------------------------
// 64x64-tile bf16 NT GEMM mainloop with ON-THE-FLY fp32->bf16 conversion.
// W is always fp32 (reg-staged: float4 loads -> pack2 -> ds_write_b128 into
// the same XOR-swizzled layout). A is fp32 (reg-staged) when !ABF, or bf16
// via global_load_lds (pre-swizzled source) when ABF.
// ---------------------------------------------------------------------------
template <bool ABF>
__device__ __forceinline__ void gemm64_core2(
    const void* __restrict__ Av, const float* __restrict__ W,
    unsigned short* smem, int bm, int bn, int tid, f32x4 acc[4])
{
    const int w = tid >> 6, lane = tid & 63, quad = lane >> 4, l15 = lane & 15;

    float4 ra[2][2], rw[2][2];
    auto loadRegs = [&](int k0) {
        if (!ABF) {
            const float* A = (const float*)Av;
            #pragma unroll
            for (int r = 0; r < 2; ++r) {
                int flat = r * 256 + tid;
                int row = flat >> 3, c = flat & 7, cs = c ^ (row & 7);
                const float* p = A + (size_t)(bm * 64 + row) * DD + k0 + cs * 8;
                ra[r][0] = *(const float4*)p;
                ra[r][1] = *(const float4*)(p + 4);
            }
        }
        #pragma unroll
        for (int r = 0; r < 2; ++r) {
            int flat = r * 256 + tid;
            int row = flat >> 3, c = flat & 7, cs = c ^ (row & 7);
            const float* p = W + (size_t)(bn * 64 + row) * DD + k0 + cs * 8;
            rw[r][0] = *(const float4*)p;
            rw[r][1] = *(const float4*)(p + 4);
        }
    };
    auto writeLDS = [&]() {
        #pragma unroll
        for (int r = 0; r < 2; ++r) {
            int flat = r * 256 + tid;
            if (!ABF)
                *(uint4*)&smem[flat * 8] = make_uint4(
                    pack2(ra[r][0].x, ra[r][0].y), pack2(ra[r][0].z, ra[r][0].w),
                    pack2(ra[r][1].x, ra[r][1].y), pack2(ra[r][1].z, ra[r][1].w));
            *(uint4*)&smem[4096 + flat * 8] = make_uint4(
                pack2(rw[r][0].x, rw[r][0].y), pack2(rw[r][0].z, rw[r][0].w),
                pack2(rw[r][1].x, rw[r][1].y), pack2(rw[r][1].z, rw[r][1].w));
        }
    };

    loadRegs(0);
    for (int k0 = 0; k0 < DD; k0 += 64) {
        if (ABF) {
            const unsigned short* A = (const unsigned short*)Av;
            #pragma unroll
            for (int r = 0; r < 2; ++r) {
                int flat = r * 256 + tid;
                int row = flat >> 3, c = flat & 7, cs = c ^ (row & 7);
                gload_lds16(A + (size_t)(bm * 64 + row) * DD + k0 + cs * 8, &smem[flat * 8]);
            }
        }
        writeLDS();
        __syncthreads();
        if (k0 + 64 < DD) loadRegs(k0 + 64);   // prefetch overlaps compute
        int mrow = w * 16 + l15;
        bf16x8 a0 = *(const bf16x8*)&smem[(mrow * 8 + (quad ^ (mrow & 7))) * 8];
        bf16x8 a1 = *(const bf16x8*)&smem[(mrow * 8 + ((quad + 4) ^ (mrow & 7))) * 8];
        #pragma unroll
        for (int nt = 0; nt < 4; ++nt) {
            int nrow = nt * 16 + l15;
            bf16x8 b0 = *(const bf16x8*)&smem[4096 + (nrow * 8 + (quad ^ (nrow & 7))) * 8];
            bf16x8 b1 = *(const bf16x8*)&smem[4096 + (nrow * 8 + ((quad + 4) ^ (nrow & 7))) * 8];
            acc[nt] = __builtin_amdgcn_mfma_f32_16x16x32_bf16(a0, b0, acc[nt], 0, 0, 0);
            acc[nt] = __builtin_amdgcn_mfma_f32_16x16x32_bf16(a1, b1, acc[nt], 0, 0, 0);
        }
        __syncthreads();
    }
}

// ---------------------------------------------------------------------------
// Kernel 1: fused Q/K/V projection GEMMs, reading fp32 inputs directly.
//  z=0: Q (scale 1/8, head-split bf16)  z=1: K (head-split bf16)
//  z=2: V (transpose -> Vt [bh][dk][s])
// ---------------------------------------------------------------------------
__global__ __launch_bounds__(256) void k_gemm_qkv(
    const float* __restrict__ xq, const float* __restrict__ xk, const float* __restrict__ xv,
    const float* __restrict__ wq, const float* __restrict__ wk, const float* __restrict__ wv,
    unsigned short* __restrict__ Qw, unsigned short* __restrict__ Kw,
    unsigned short* __restrict__ Vt)
{
    __shared__ unsigned short smem[8192];
    const int z = blockIdx.z;
    const float* A = (z == 0) ? xq : (z == 1) ? xk : xv;
    const float* W = (z == 0) ? wq : (z == 1) ? wk : wv;
    const int bm = blockIdx.x, bn = blockIdx.y;
    const int tid = threadIdx.x, w = tid >> 6, lane = tid & 63, quad = lane >> 4, l15 = lane & 15;

    f32x4 acc[4];
    #pragma unroll
    for (int i = 0; i < 4; ++i) acc[i] = (f32x4){0.f, 0.f, 0.f, 0.f};
    gemm64_core2<false>(A, W, smem, bm, bn, tid, acc);

    if (z != 2) {
        const float sc = (z == 0) ? 0.125f : 1.0f;
        unsigned short* dbf = (z == 0) ? Qw : Kw;
        #pragma unroll
        for (int nt = 0; nt < 4; ++nt) {
            int n = bn * 64 + nt * 16 + l15;
            int h = n >> 6, dk = n & 63;
            #pragma unroll
            for (int rg = 0; rg < 4; ++rg) {
                int m = bm * 64 + w * 16 + quad * 4 + rg;
                int b = m >> 11, s = m & (SS - 1);
                dbf[(((size_t)(b * HH + h) * SS + s) << 6) + dk] = f2bf(acc[nt][rg] * sc);
            }
        }
    } else {
        unsigned short* T = smem;   // [64][72] = 9216 B, fits in 16 KB
        #pragma unroll
        for (int nt = 0; nt < 4; ++nt)
            #pragma unroll
            for (int rg = 0; rg < 4; ++rg)
                T[(w * 16 + quad * 4 + rg) * 72 + nt * 16 + l15] = f2bf(acc[nt][rg]);
        __syncthreads();
        int n = tid >> 2, s0 = (tid & 3) * 16;
        int ng = bn * 64 + n, h = ng >> 6, dk = ng & 63;
        int mg = bm * 64 + s0, b = mg >> 11, s = mg & (SS - 1);
        unsigned vals[8];
        #pragma unroll
        for (int i = 0; i < 8; ++i)
            vals[i] = (unsigned)T[(s0 + 2*i) * 72 + n] | ((unsigned)T[(s0 + 2*i + 1) * 72 + n] << 16);
        unsigned short* dp = Vt + ((size_t)(b * HH + h) * DKK + dk) * SS + s;
        ((uint4*)dp)[0] = make_uint4(vals[0], vals[1], vals[2], vals[3]);
        ((uint4*)dp)[1] = make_uint4(vals[4], vals[5], vals[6], vals[7]);
    }
}

// ---------------------------------------------------------------------------
// Kernel 2: attention pass 1, K-SPLIT (ks in {0,1}, 1024 keys each).
// 1024 blocks -> 4 waves/SIMD (2x the TLP of the unsplit version; the kernel
// was latency-bound at 2 waves/SIMD). No-max online softmax => partials merge
// linearly. Writes UNNORMALIZED fp32 partial O and partial lsum to the
// P-region scratch (dead before k_pwrite).
// XCD swizzle: all 64 blocks of a bh on one XCD (K+V L2-resident).
// ---------------------------------------------------------------------------
__global__ __launch_bounds__(256) void k_attn(
    const unsigned short* __restrict__ Qw, const unsigned short* __restrict__ Kw,
    const unsigned short* __restrict__ Vt, float* __restrict__ Opart,
    float* __restrict__ Lpart)
{
    __shared__ unsigned short Kl[2][4096];      // [buf][64 s][64 dk] swizzled
    __shared__ unsigned short Vl[2][4096];      // [buf][64 dk][64 s] swizzled
    __shared__ unsigned short Pl[2][4][16][68]; // per-wave P round-trip

    const int id = blockIdx.x;                  // 1024 blocks
    const int xcd = id & 7, j = id >> 3;        // j in [0,128)
    const int bh = xcd * 2 + (j >> 6);
    const int rem = j & 63, qt = rem >> 1, ks = rem & 1;

    const int tid = threadIdx.x, w = tid >> 6, lane = tid & 63, quad = lane >> 4, l15 = lane & 15;

    const unsigned short* Qb = Qw + ((size_t)bh * SS + qt * 64 + w * 16) * DKK;
    const unsigned short* Kb = Kw + (size_t)bh * SS * DKK;
    const unsigned short* Vb = Vt + (size_t)bh * DKK * SS;

    bf16x8 qa0 = *(const bf16x8*)&Qb[l15 * DKK + quad * 8];
    bf16x8 qa1 = *(const bf16x8*)&Qb[l15 * DKK + 32 + quad * 8];

    f32x4 oacc[4];
    #pragma unroll
    for (int i = 0; i < 4; ++i) oacc[i] = (f32x4){0.f, 0.f, 0.f, 0.f};
    float lsum[4] = {0.f, 0.f, 0.f, 0.f};

    auto stage = [&](int kt, int b) {
        #pragma unroll
        for (int r = 0; r < 2; ++r) {
            int flat = r * 256 + tid;
            int row = flat >> 3, c = flat & 7, cs = c ^ (row & 7);
            gload_lds16(Kb + (size_t)(kt * 64 + row) * DKK + cs * 8, &Kl[b][flat * 8]);
        }
        #pragma unroll
        for (int r = 0; r < 2; ++r) {
            int flat = r * 256 + tid;
            int row = flat >> 3, c = flat & 7, cs = c ^ (row & 7);
            gload_lds16(Vb + (size_t)row * SS + kt * 64 + cs * 8, &Vl[b][flat * 8]);
        }
    };

    const int NT = 16;                          // 16 key-tiles per split
    const int base = ks * NT;
    stage(base + 0, 0);
    stage(base + 1, 1);

    for (int i = 0; i < NT; ++i) {
        if (i < NT - 1) { VM_WAIT4; } else { VM_WAIT0; }
        __builtin_amdgcn_s_barrier();
        __builtin_amdgcn_sched_barrier(0);
        const int b = i & 1;

        f32x4 sa[4];
        #pragma unroll
        for (int ii = 0; ii < 4; ++ii) sa[ii] = (f32x4){0.f, 0.f, 0.f, 0.f};
        __builtin_amdgcn_s_setprio(1);
        #pragma unroll
        for (int jt = 0; jt < 4; ++jt) {
            int row = jt * 16 + l15;
            bf16x8 b0 = *(const bf16x8*)&Kl[b][(row * 8 + (quad ^ (row & 7))) * 8];
            bf16x8 b1 = *(const bf16x8*)&Kl[b][(row * 8 + ((quad + 4) ^ (row & 7))) * 8];
            sa[jt] = __builtin_amdgcn_mfma_f32_16x16x32_bf16(qa0, b0, sa[jt], 0, 0, 0);
            sa[jt] = __builtin_amdgcn_mfma_f32_16x16x32_bf16(qa1, b1, sa[jt], 0, 0, 0);
        }
        __builtin_amdgcn_s_setprio(0);

        float ev[4][4];
        #pragma unroll
        for (int jt = 0; jt < 4; ++jt)
            #pragma unroll
            for (int rg = 0; rg < 4; ++rg)
                ev[jt][rg] = __expf(sa[jt][rg]);
        #pragma unroll
        for (int rg = 0; rg < 4; ++rg) {
            float s = ev[0][rg] + ev[1][rg] + ev[2][rg] + ev[3][rg];
            s += __shfl_xor(s, 1);
            s += __shfl_xor(s, 2);
            s += __shfl_xor(s, 4);
            s += __shfl_xor(s, 8);
            lsum[rg] += s;
        }
        #pragma unroll
        for (int jt = 0; jt < 4; ++jt)
            #pragma unroll
            for (int rg = 0; rg < 4; ++rg)
                Pl[b][w][quad * 4 + rg][jt * 16 + l15] = f2bf(ev[jt][rg]);
        bf16x8 pa0 = *(const bf16x8*)&Pl[b][w][l15][quad * 8];
        bf16x8 pa1 = *(const bf16x8*)&Pl[b][w][l15][32 + quad * 8];

        __builtin_amdgcn_s_setprio(1);
        #pragma unroll
        for (int dt = 0; dt < 4; ++dt) {
            int row = dt * 16 + l15;
            bf16x8 v0 = *(const bf16x8*)&Vl[b][(row * 8 + (quad ^ (row & 7))) * 8];
            bf16x8 v1 = *(const bf16x8*)&Vl[b][(row * 8 + ((quad + 4) ^ (row & 7))) * 8];
            oacc[dt] = __builtin_amdgcn_mfma_f32_16x16x32_bf16(pa0, v0, oacc[dt], 0, 0, 0);
            oacc[dt] = __builtin_amdgcn_mfma_f32_16x16x32_bf16(pa1, v1, oacc[dt], 0, 0, 0);
        }
        __builtin_amdgcn_s_setprio(0);

        __builtin_amdgcn_s_barrier();           // all waves done with buf b
        if (i + 2 < NT) stage(base + i + 2, b);
    }

    // partial epilogue: fp32 O partial + lsum partial (unnormalized)
    const int srow = qt * 64 + w * 16 + quad * 4;
    float* Ob = Opart + (((size_t)(bh * 2 + ks) * SS + srow) << 6);
    #pragma unroll
    for (int dt = 0; dt < 4; ++dt)
        #pragma unroll
        for (int rg = 0; rg < 4; ++rg)
            Ob[((size_t)rg << 6) + dt * 16 + l15] = oacc[dt][rg];

    if (l15 == 0) {
        #pragma unroll
        for (int rg = 0; rg < 4; ++rg)
            Lpart[(size_t)(bh * 2 + ks) * SS + srow + rg] = lsum[rg];
    }
}

// ---------------------------------------------------------------------------
// Kernel 2b: merge the two K-split partials -> AO (bf16, head-merged layout)
// and Linv (fp32). 512 blocks x 256 threads; ~22 MB traffic (~5 us).
// ---------------------------------------------------------------------------
__global__ __launch_bounds__(256) void k_merge(
    const float* __restrict__ Opart, const float* __restrict__ Lpart,
    unsigned short* __restrict__ AO, float* __restrict__ Linv)
{
    const int qt = blockIdx.x, bh = blockIdx.y;
    const int tid = threadIdx.x;
    const int r = tid >> 2, c0 = (tid & 3) * 16;
    const int s = qt * 64 + r;

    const float l0 = Lpart[(size_t)(bh * 2 + 0) * SS + s];
    const float l1 = Lpart[(size_t)(bh * 2 + 1) * SS + s];
    const float linv = 1.0f / (l0 + l1);

    const float* p0 = Opart + ((((size_t)(bh * 2 + 0) * SS + s) << 6) + c0);
    const float* p1 = Opart + ((((size_t)(bh * 2 + 1) * SS + s) << 6) + c0);
    float o[16];
    #pragma unroll
    for (int i = 0; i < 4; ++i) {
        float4 a = ((const float4*)p0)[i];
        float4 b = ((const float4*)p1)[i];
        o[i*4+0] = (a.x + b.x) * linv;
        o[i*4+1] = (a.y + b.y) * linv;
        o[i*4+2] = (a.z + b.z) * linv;
        o[i*4+3] = (a.w + b.w) * linv;
    }
    const int b2 = bh >> 3, h = bh & 7;
    unsigned short* dp = AO + (((size_t)(b2 * SS + s)) << 9) + h * 64 + c0;
    ((uint4*)dp)[0] = make_uint4(pack2(o[0],o[1]), pack2(o[2],o[3]),
                                 pack2(o[4],o[5]), pack2(o[6],o[7]));
    ((uint4*)dp)[1] = make_uint4(pack2(o[8],o[9]), pack2(o[10],o[11]),
                                 pack2(o[12],o[13]), pack2(o[14],o[15]));

    if ((tid & 3) == 0) Linv[(size_t)bh * SS + s] = linv;
}

// ---------------------------------------------------------------------------
// Kernel 3: p_attn writer. 2048 blocks (8/CU), XCD-swizzled, float4 full-line
// nontemporal stores via per-wave LDS transpose.
// ---------------------------------------------------------------------------
__global__ __launch_bounds__(256) void k_pwrite(
    const unsigned short* __restrict__ Qw, const unsigned short* __restrict__ Kw,
    const float* __restrict__ Linv, float* __restrict__ P)
{
    __shared__ float Tl[4][16][68];             // per-wave transpose tile
    const int id = blockIdx.x;                  // 2048 blocks
    const int xcd = id & 7, j = id >> 3;        // j in [0,256)
    const int bh = xcd * 2 + (j >> 7);
    const int rem = j & 127, qt = rem >> 2, ks = rem & 3;
    const int tid = threadIdx.x, w = tid >> 6, lane = tid & 63, quad = lane >> 4, l15 = lane & 15;

    const unsigned short* Qb = Qw + ((size_t)bh * SS + qt * 64 + w * 16) * DKK;
    bf16x8 qa0 = *(const bf16x8*)&Qb[l15 * DKK + quad * 8];
    bf16x8 qa1 = *(const bf16x8*)&Qb[l15 * DKK + 32 + quad * 8];

    float linv[4];
    #pragma unroll
    for (int rg = 0; rg < 4; ++rg)
        linv[rg] = Linv[(size_t)bh * SS + qt * 64 + w * 16 + quad * 4 + rg];

    const unsigned short* Kb = Kw + (size_t)bh * SS * DKK + (size_t)ks * 512 * DKK;
    float* Pb = P + (((size_t)bh * SS + qt * 64 + w * 16) << 11) + ks * 512;

    for (int kt = 0; kt < 8; ++kt) {
        const unsigned short* Kt = Kb + (size_t)kt * 64 * DKK;
        #pragma unroll
        for (int jt = 0; jt < 4; ++jt) {
            bf16x8 b0 = *(const bf16x8*)&Kt[(jt * 16 + l15) * DKK + quad * 8];
            bf16x8 b1 = *(const bf16x8*)&Kt[(jt * 16 + l15) * DKK + 32 + quad * 8];
            f32x4 sa = (f32x4){0.f, 0.f, 0.f, 0.f};
            sa = __builtin_amdgcn_mfma_f32_16x16x32_bf16(qa0, b0, sa, 0, 0, 0);
            sa = __builtin_amdgcn_mfma_f32_16x16x32_bf16(qa1, b1, sa, 0, 0, 0);
            #pragma unroll
            for (int rg = 0; rg < 4; ++rg)
                Tl[w][quad * 4 + rg][jt * 16 + l15] = __expf(sa[rg]) * linv[rg];
        }
        #pragma unroll
        for (int c = 0; c < 4; ++c) {
            int row = c * 4 + quad;
            f32x4 val = *(const f32x4*)&Tl[w][row][l15 * 4];
            __builtin_nontemporal_store(val,
                (f32x4*)(Pb + ((size_t)row << 11) + kt * 64 + l15 * 4));
        }
    }
}

// ---------------------------------------------------------------------------
// Kernel 4: output projection. A = AO (bf16, gload_lds); W = wo (fp32 input).
// ---------------------------------------------------------------------------
__global__ __launch_bounds__(256) void k_gemm_o(
    const unsigned short* __restrict__ A, const float* __restrict__ W,
    float* __restrict__ out)
{
    __shared__ unsigned short smem[8192];
    const int bm = blockIdx.x, bn = blockIdx.y;
    const int tid = threadIdx.x, w = tid >> 6, lane = tid & 63, quad = lane >> 4, l15 = lane & 15;
    f32x4 acc[4];
    #pragma unroll
    for (int i = 0; i < 4; ++i) acc[i] = (f32x4){0.f, 0.f, 0.f, 0.f};
    gemm64_core2<true>(A, W, smem, bm, bn, tid, acc);
    #pragma unroll
    for (int nt = 0; nt < 4; ++nt)
        #pragma unroll
        for (int rg = 0; rg < 4; ++rg)
            out[(size_t)(bm * 64 + w * 16 + quad * 4 + rg) * DD + bn * 64 + nt * 16 + l15] =
                acc[nt][rg];
}

extern "C" void kernel_launch(void* const* d_in, const int* in_sizes, int n_in,
                              void* d_out, int out_size, void* d_ws, size_t ws_size,
                              hipStream_t stream) {
    const float* q  = (const float*)d_in[0];
    const float* k  = (const float*)d_in[1];
    const float* v  = (const float*)d_in[2];
    const float* wq = (const float*)d_in[3];
    const float* wk = (const float*)d_in[4];
    const float* wv = (const float*)d_in[5];
    const float* wo = (const float*)d_in[6];

    float* out = (float*)d_out;                         // [4096, 512] fp32
    float* P   = out + (size_t)BB * SS * DD;            // [2,8,2048,2048] fp32

    const size_t NX = (size_t)BB * SS * DD;   // 2,097,152

    // P-region scratch: K-split partials (17.3 MB), dead before k_pwrite.
    float* Opart = P;                                   // [32][2048][64] fp32
    float* Lpart = Opart + (size_t)32 * SS * DKK;       // [32][2048] fp32

    // d_ws: everything that must survive the P-write (~16.9 MB).
    unsigned short* Qw   = (unsigned short*)d_ws;
    unsigned short* Kw   = Qw + NX;
    unsigned short* Vt   = Kw + NX;
    unsigned short* AO   = Vt + NX;
    float*          Linv = (float*)(AO + NX);           // [bh][s], 128 KB

    k_gemm_qkv<<<dim3(64, 8, 3), 256, 0, stream>>>(q, k, v, wq, wk, wv, Qw, Kw, Vt);
    k_attn<<<dim3(1024), 256, 0, stream>>>(Qw, Kw, Vt, Opart, Lpart);
    k_merge<<<dim3(32, 16), 256, 0, stream>>>(Opart, Lpart, AO, Linv);
    k_pwrite<<<dim3(2048), 256, 0, stream>>>(Qw, Kw, Linv, P);
    k_gemm_o<<<dim3(64, 8), 256, 0, stream>>>(AO, wo, out);
}

// Round 8
// 397.494 us; speedup vs baseline: 1.0192x; 1.0192x over previous
//
#include <hip/hip_runtime.h>
#include <hip/hip_bf16.h>
#include <cstdint>
#include <cstddef>

// B=2, S=2048, D=512, H=8, DK=64
#define BB 2
#define SS 2048
#define DD 512
#define HH 8
#define DKK 64

typedef __attribute__((ext_vector_type(8))) short bf16x8;   // 8 bf16 = 4 VGPRs
typedef __attribute__((ext_vector_type(4))) float f32x4;

__device__ __forceinline__ unsigned short f2bf(float f) {
    union { float f; unsigned u; } v; v.f = f;
    unsigned u = v.u;
    return (unsigned short)((u + 0x7fffu + ((u >> 16) & 1u)) >> 16);   // RNE
}
__device__ __forceinline__ unsigned pack2(float a, float b) {
    return (unsigned)f2bf(a) | ((unsigned)f2bf(b) << 16);
}

typedef const __attribute__((address_space(1))) unsigned int* gp_t;
typedef __attribute__((address_space(3))) unsigned int* lp_t;
__device__ __forceinline__ void gload_lds16(const void* g, void* l) {
    __builtin_amdgcn_global_load_lds((gp_t)g, (lp_t)l, 16, 0, 0);
}

#define VM_WAIT4 asm volatile("s_waitcnt vmcnt(4)" ::: "memory")
#define VM_WAIT0 asm volatile("s_waitcnt vmcnt(0)" ::: "memory")

// ---------------------------------------------------------------------------
// 64x64-tile bf16 NT GEMM mainloop with ON-THE-FLY fp32->bf16 conversion.
// W is always fp32 (reg-staged: float4 loads -> pack2 -> ds_write_b128 into
// the same XOR-swizzled layout). A is fp32 (reg-staged) when !ABF, or bf16
// via global_load_lds (pre-swizzled source) when ABF.
// ---------------------------------------------------------------------------
template <bool ABF>
__device__ __forceinline__ void gemm64_core2(
    const void* __restrict__ Av, const float* __restrict__ W,
    unsigned short* smem, int bm, int bn, int tid, f32x4 acc[4])
{
    const int w = tid >> 6, lane = tid & 63, quad = lane >> 4, l15 = lane & 15;

    float4 ra[2][2], rw[2][2];
    auto loadRegs = [&](int k0) {
        if (!ABF) {
            const float* A = (const float*)Av;
            #pragma unroll
            for (int r = 0; r < 2; ++r) {
                int flat = r * 256 + tid;
                int row = flat >> 3, c = flat & 7, cs = c ^ (row & 7);
                const float* p = A + (size_t)(bm * 64 + row) * DD + k0 + cs * 8;
                ra[r][0] = *(const float4*)p;
                ra[r][1] = *(const float4*)(p + 4);
            }
        }
        #pragma unroll
        for (int r = 0; r < 2; ++r) {
            int flat = r * 256 + tid;
            int row = flat >> 3, c = flat & 7, cs = c ^ (row & 7);
            const float* p = W + (size_t)(bn * 64 + row) * DD + k0 + cs * 8;
            rw[r][0] = *(const float4*)p;
            rw[r][1] = *(const float4*)(p + 4);
        }
    };
    auto writeLDS = [&]() {
        #pragma unroll
        for (int r = 0; r < 2; ++r) {
            int flat = r * 256 + tid;
            if (!ABF)
                *(uint4*)&smem[flat * 8] = make_uint4(
                    pack2(ra[r][0].x, ra[r][0].y), pack2(ra[r][0].z, ra[r][0].w),
                    pack2(ra[r][1].x, ra[r][1].y), pack2(ra[r][1].z, ra[r][1].w));
            *(uint4*)&smem[4096 + flat * 8] = make_uint4(
                pack2(rw[r][0].x, rw[r][0].y), pack2(rw[r][0].z, rw[r][0].w),
                pack2(rw[r][1].x, rw[r][1].y), pack2(rw[r][1].z, rw[r][1].w));
        }
    };

    loadRegs(0);
    for (int k0 = 0; k0 < DD; k0 += 64) {
        if (ABF) {
            const unsigned short* A = (const unsigned short*)Av;
            #pragma unroll
            for (int r = 0; r < 2; ++r) {
                int flat = r * 256 + tid;
                int row = flat >> 3, c = flat & 7, cs = c ^ (row & 7);
                gload_lds16(A + (size_t)(bm * 64 + row) * DD + k0 + cs * 8, &smem[flat * 8]);
            }
        }
        writeLDS();
        __syncthreads();
        if (k0 + 64 < DD) loadRegs(k0 + 64);   // prefetch overlaps compute
        int mrow = w * 16 + l15;
        bf16x8 a0 = *(const bf16x8*)&smem[(mrow * 8 + (quad ^ (mrow & 7))) * 8];
        bf16x8 a1 = *(const bf16x8*)&smem[(mrow * 8 + ((quad + 4) ^ (mrow & 7))) * 8];
        #pragma unroll
        for (int nt = 0; nt < 4; ++nt) {
            int nrow = nt * 16 + l15;
            bf16x8 b0 = *(const bf16x8*)&smem[4096 + (nrow * 8 + (quad ^ (nrow & 7))) * 8];
            bf16x8 b1 = *(const bf16x8*)&smem[4096 + (nrow * 8 + ((quad + 4) ^ (nrow & 7))) * 8];
            acc[nt] = __builtin_amdgcn_mfma_f32_16x16x32_bf16(a0, b0, acc[nt], 0, 0, 0);
            acc[nt] = __builtin_amdgcn_mfma_f32_16x16x32_bf16(a1, b1, acc[nt], 0, 0, 0);
        }
        __syncthreads();
    }
}

// ---------------------------------------------------------------------------
// Kernel 1: fused Q/K/V projection GEMMs, reading fp32 inputs directly.
//  z=0: Q (scale 1/8, head-split bf16)  z=1: K (head-split bf16)
//  z=2: V (transpose -> Vt [bh][dk][s])
// ---------------------------------------------------------------------------
__global__ __launch_bounds__(256) void k_gemm_qkv(
    const float* __restrict__ xq, const float* __restrict__ xk, const float* __restrict__ xv,
    const float* __restrict__ wq, const float* __restrict__ wk, const float* __restrict__ wv,
    unsigned short* __restrict__ Qw, unsigned short* __restrict__ Kw,
    unsigned short* __restrict__ Vt)
{
    __shared__ unsigned short smem[8192];
    const int z = blockIdx.z;
    const float* A = (z == 0) ? xq : (z == 1) ? xk : xv;
    const float* W = (z == 0) ? wq : (z == 1) ? wk : wv;
    const int bm = blockIdx.x, bn = blockIdx.y;
    const int tid = threadIdx.x, w = tid >> 6, lane = tid & 63, quad = lane >> 4, l15 = lane & 15;

    f32x4 acc[4];
    #pragma unroll
    for (int i = 0; i < 4; ++i) acc[i] = (f32x4){0.f, 0.f, 0.f, 0.f};
    gemm64_core2<false>(A, W, smem, bm, bn, tid, acc);

    if (z != 2) {
        const float sc = (z == 0) ? 0.125f : 1.0f;
        unsigned short* dbf = (z == 0) ? Qw : Kw;
        #pragma unroll
        for (int nt = 0; nt < 4; ++nt) {
            int n = bn * 64 + nt * 16 + l15;
            int h = n >> 6, dk = n & 63;
            #pragma unroll
            for (int rg = 0; rg < 4; ++rg) {
                int m = bm * 64 + w * 16 + quad * 4 + rg;
                int b = m >> 11, s = m & (SS - 1);
                dbf[(((size_t)(b * HH + h) * SS + s) << 6) + dk] = f2bf(acc[nt][rg] * sc);
            }
        }
    } else {
        unsigned short* T = smem;   // [64][72] = 9216 B, fits in 16 KB
        #pragma unroll
        for (int nt = 0; nt < 4; ++nt)
            #pragma unroll
            for (int rg = 0; rg < 4; ++rg)
                T[(w * 16 + quad * 4 + rg) * 72 + nt * 16 + l15] = f2bf(acc[nt][rg]);
        __syncthreads();
        int n = tid >> 2, s0 = (tid & 3) * 16;
        int ng = bn * 64 + n, h = ng >> 6, dk = ng & 63;
        int mg = bm * 64 + s0, b = mg >> 11, s = mg & (SS - 1);
        unsigned vals[8];
        #pragma unroll
        for (int i = 0; i < 8; ++i)
            vals[i] = (unsigned)T[(s0 + 2*i) * 72 + n] | ((unsigned)T[(s0 + 2*i + 1) * 72 + n] << 16);
        unsigned short* dp = Vt + ((size_t)(b * HH + h) * DKK + dk) * SS + s;
        ((uint4*)dp)[0] = make_uint4(vals[0], vals[1], vals[2], vals[3]);
        ((uint4*)dp)[1] = make_uint4(vals[4], vals[5], vals[6], vals[7]);
    }
}

// ---------------------------------------------------------------------------
// Kernel 2: attention pass 1 (round-3 version, best measured). Q pre-scaled
// by 1/8. XCD-locality swizzle; K,V staged once per block in LDS,
// double-buffered with counted vmcnt(4) + raw s_barrier.
// Emits AO (bf16) and Linv (fp32).
// ---------------------------------------------------------------------------
__global__ __launch_bounds__(256) void k_attn(
    const unsigned short* __restrict__ Qw, const unsigned short* __restrict__ Kw,
    const unsigned short* __restrict__ Vt, unsigned short* __restrict__ AO,
    float* __restrict__ Linv)
{
    __shared__ unsigned short Kl[2][4096];      // [buf][64 s][64 dk] swizzled
    __shared__ unsigned short Vl[2][4096];      // [buf][64 dk][64 s] swizzled
    __shared__ unsigned short Pl[2][4][16][68]; // per-wave P round-trip

    const int id = blockIdx.x;                  // 512 blocks
    const int xcd = id & 7, j = id >> 3;
    const int bh = xcd * 2 + (j >> 5), qt = j & 31;

    const int tid = threadIdx.x, w = tid >> 6, lane = tid & 63, quad = lane >> 4, l15 = lane & 15;

    const unsigned short* Qb = Qw + ((size_t)bh * SS + qt * 64 + w * 16) * DKK;
    const unsigned short* Kb = Kw + (size_t)bh * SS * DKK;
    const unsigned short* Vb = Vt + (size_t)bh * DKK * SS;

    bf16x8 qa0 = *(const bf16x8*)&Qb[l15 * DKK + quad * 8];
    bf16x8 qa1 = *(const bf16x8*)&Qb[l15 * DKK + 32 + quad * 8];

    f32x4 oacc[4];
    #pragma unroll
    for (int i = 0; i < 4; ++i) oacc[i] = (f32x4){0.f, 0.f, 0.f, 0.f};
    float lsum[4] = {0.f, 0.f, 0.f, 0.f};

    auto stage = [&](int kt, int b) {
        #pragma unroll
        for (int r = 0; r < 2; ++r) {
            int flat = r * 256 + tid;
            int row = flat >> 3, c = flat & 7, cs = c ^ (row & 7);
            gload_lds16(Kb + (size_t)(kt * 64 + row) * DKK + cs * 8, &Kl[b][flat * 8]);
        }
        #pragma unroll
        for (int r = 0; r < 2; ++r) {
            int flat = r * 256 + tid;
            int row = flat >> 3, c = flat & 7, cs = c ^ (row & 7);
            gload_lds16(Vb + (size_t)row * SS + kt * 64 + cs * 8, &Vl[b][flat * 8]);
        }
    };

    stage(0, 0);
    stage(1, 1);

    const int NT = SS / 64;   // 32
    for (int kt = 0; kt < NT; ++kt) {
        if (kt < NT - 1) { VM_WAIT4; } else { VM_WAIT0; }   // tile kt staged
        __builtin_amdgcn_s_barrier();
        __builtin_amdgcn_sched_barrier(0);
        const int b = kt & 1;

        f32x4 sa[4];
        #pragma unroll
        for (int i = 0; i < 4; ++i) sa[i] = (f32x4){0.f, 0.f, 0.f, 0.f};
        __builtin_amdgcn_s_setprio(1);
        #pragma unroll
        for (int jt = 0; jt < 4; ++jt) {
            int row = jt * 16 + l15;
            bf16x8 b0 = *(const bf16x8*)&Kl[b][(row * 8 + (quad ^ (row & 7))) * 8];
            bf16x8 b1 = *(const bf16x8*)&Kl[b][(row * 8 + ((quad + 4) ^ (row & 7))) * 8];
            sa[jt] = __builtin_amdgcn_mfma_f32_16x16x32_bf16(qa0, b0, sa[jt], 0, 0, 0);
            sa[jt] = __builtin_amdgcn_mfma_f32_16x16x32_bf16(qa1, b1, sa[jt], 0, 0, 0);
        }
        __builtin_amdgcn_s_setprio(0);

        float ev[4][4];
        #pragma unroll
        for (int jt = 0; jt < 4; ++jt)
            #pragma unroll
            for (int rg = 0; rg < 4; ++rg)
                ev[jt][rg] = __expf(sa[jt][rg]);
        #pragma unroll
        for (int rg = 0; rg < 4; ++rg) {
            float s = ev[0][rg] + ev[1][rg] + ev[2][rg] + ev[3][rg];
            s += __shfl_xor(s, 1);
            s += __shfl_xor(s, 2);
            s += __shfl_xor(s, 4);
            s += __shfl_xor(s, 8);
            lsum[rg] += s;
        }
        #pragma unroll
        for (int jt = 0; jt < 4; ++jt)
            #pragma unroll
            for (int rg = 0; rg < 4; ++rg)
                Pl[b][w][quad * 4 + rg][jt * 16 + l15] = f2bf(ev[jt][rg]);
        bf16x8 pa0 = *(const bf16x8*)&Pl[b][w][l15][quad * 8];
        bf16x8 pa1 = *(const bf16x8*)&Pl[b][w][l15][32 + quad * 8];

        __builtin_amdgcn_s_setprio(1);
        #pragma unroll
        for (int dt = 0; dt < 4; ++dt) {
            int row = dt * 16 + l15;
            bf16x8 v0 = *(const bf16x8*)&Vl[b][(row * 8 + (quad ^ (row & 7))) * 8];
            bf16x8 v1 = *(const bf16x8*)&Vl[b][(row * 8 + ((quad + 4) ^ (row & 7))) * 8];
            oacc[dt] = __builtin_amdgcn_mfma_f32_16x16x32_bf16(pa0, v0, oacc[dt], 0, 0, 0);
            oacc[dt] = __builtin_amdgcn_mfma_f32_16x16x32_bf16(pa1, v1, oacc[dt], 0, 0, 0);
        }
        __builtin_amdgcn_s_setprio(0);

        __builtin_amdgcn_s_barrier();           // all waves done with buf b
        if (kt + 2 < NT) stage(kt + 2, b);      // overwrite buf b with tile kt+2
    }

    float linv[4];
    #pragma unroll
    for (int rg = 0; rg < 4; ++rg) linv[rg] = 1.0f / lsum[rg];

    const int b2 = bh >> 3, h = bh & 7;
    const int srow = qt * 64 + w * 16 + quad * 4;
    #pragma unroll
    for (int dt = 0; dt < 4; ++dt)
        #pragma unroll
        for (int rg = 0; rg < 4; ++rg)
            AO[((size_t)(b2 * SS + srow + rg) << 9) + h * 64 + dt * 16 + l15] =
                f2bf(oacc[dt][rg] * linv[rg]);

    if (l15 == 0) {
        #pragma unroll
        for (int rg = 0; rg < 4; ++rg)
            Linv[(size_t)bh * SS + srow + rg] = linv[rg];
    }
}

// ---------------------------------------------------------------------------
// Kernel 3: FUSED p_attn writer + output projection (independent workloads,
// one dispatch -> one fewer launch boundary and full tail overlap).
// Blocks [0,512): out = AO @ wo^T (fp32 epilogue).
// Blocks [512,2560): P writer (XCD-swizzled; 512 % 8 == 0 keeps mapping).
// LDS: union of the two paths' needs, declared as uint4 (16B-aligned base —
// the char[] declaration in the previous revision did not guarantee the
// alignment its ds_*_b128 accesses assume).
// ---------------------------------------------------------------------------
__global__ __launch_bounds__(256) void k_pw_o(
    const unsigned short* __restrict__ Qw, const unsigned short* __restrict__ Kw,
    const float* __restrict__ Linv, float* __restrict__ P,
    const unsigned short* __restrict__ AO, const float* __restrict__ wo,
    float* __restrict__ out)
{
    __shared__ uint4 ldsbuf[1088];              // 17408 B, 16B-aligned
    const int tid = threadIdx.x, w = tid >> 6, lane = tid & 63, quad = lane >> 4, l15 = lane & 15;

    if (blockIdx.x < 512) {
        // ---- output projection ----
        unsigned short* smem = (unsigned short*)ldsbuf;
        const int bid = blockIdx.x;
        const int bm = bid >> 3, bn = bid & 7;
        f32x4 acc[4];
        #pragma unroll
        for (int i = 0; i < 4; ++i) acc[i] = (f32x4){0.f, 0.f, 0.f, 0.f};
        gemm64_core2<true>(AO, wo, smem, bm, bn, tid, acc);
        #pragma unroll
        for (int nt = 0; nt < 4; ++nt)
            #pragma unroll
            for (int rg = 0; rg < 4; ++rg)
                out[(size_t)(bm * 64 + w * 16 + quad * 4 + rg) * DD + bn * 64 + nt * 16 + l15] =
                    acc[nt][rg];
        return;
    }

    // ---- p_attn writer ----
    float (*Tl)[16][68] = (float(*)[16][68])ldsbuf;     // [4][16][68]
    const int id = blockIdx.x - 512;            // [0,2048)
    const int xcd = id & 7, j = id >> 3;        // j in [0,256)
    const int bh = xcd * 2 + (j >> 7);
    const int rem = j & 127, qt = rem >> 2, ks = rem & 3;

    const unsigned short* Qb = Qw + ((size_t)bh * SS + qt * 64 + w * 16) * DKK;
    bf16x8 qa0 = *(const bf16x8*)&Qb[l15 * DKK + quad * 8];
    bf16x8 qa1 = *(const bf16x8*)&Qb[l15 * DKK + 32 + quad * 8];

    float linv[4];
    #pragma unroll
    for (int rg = 0; rg < 4; ++rg)
        linv[rg] = Linv[(size_t)bh * SS + qt * 64 + w * 16 + quad * 4 + rg];

    const unsigned short* Kb = Kw + (size_t)bh * SS * DKK + (size_t)ks * 512 * DKK;
    float* Pb = P + (((size_t)bh * SS + qt * 64 + w * 16) << 11) + ks * 512;

    for (int kt = 0; kt < 8; ++kt) {
        const unsigned short* Kt = Kb + (size_t)kt * 64 * DKK;
        #pragma unroll
        for (int jt = 0; jt < 4; ++jt) {
            bf16x8 b0 = *(const bf16x8*)&Kt[(jt * 16 + l15) * DKK + quad * 8];
            bf16x8 b1 = *(const bf16x8*)&Kt[(jt * 16 + l15) * DKK + 32 + quad * 8];
            f32x4 sa = (f32x4){0.f, 0.f, 0.f, 0.f};
            sa = __builtin_amdgcn_mfma_f32_16x16x32_bf16(qa0, b0, sa, 0, 0, 0);
            sa = __builtin_amdgcn_mfma_f32_16x16x32_bf16(qa1, b1, sa, 0, 0, 0);
            #pragma unroll
            for (int rg = 0; rg < 4; ++rg)
                Tl[w][quad * 4 + rg][jt * 16 + l15] = __expf(sa[rg]) * linv[rg];
        }
        // transpose: 16 lanes per row -> 256B contiguous float4 stores
        #pragma unroll
        for (int c = 0; c < 4; ++c) {
            int row = c * 4 + quad;
            f32x4 val = *(const f32x4*)&Tl[w][row][l15 * 4];
            __builtin_nontemporal_store(val,
                (f32x4*)(Pb + ((size_t)row << 11) + kt * 64 + l15 * 4));
        }
    }
}

extern "C" void kernel_launch(void* const* d_in, const int* in_sizes, int n_in,
                              void* d_out, int out_size, void* d_ws, size_t ws_size,
                              hipStream_t stream) {
    const float* q  = (const float*)d_in[0];
    const float* k  = (const float*)d_in[1];
    const float* v  = (const float*)d_in[2];
    const float* wq = (const float*)d_in[3];
    const float* wk = (const float*)d_in[4];
    const float* wv = (const float*)d_in[5];
    const float* wo = (const float*)d_in[6];

    float* out = (float*)d_out;                         // [4096, 512] fp32
    float* P   = out + (size_t)BB * SS * DD;            // [2,8,2048,2048] fp32

    const size_t NX = (size_t)BB * SS * DD;   // 2,097,152

    // d_ws: everything that must survive the P-write (~16.9 MB).
    unsigned short* Qw   = (unsigned short*)d_ws;
    unsigned short* Kw   = Qw + NX;
    unsigned short* Vt   = Kw + NX;
    unsigned short* AO   = Vt + NX;
    float*          Linv = (float*)(AO + NX);           // [bh][s], 128 KB

    k_gemm_qkv<<<dim3(64, 8, 3), 256, 0, stream>>>(q, k, v, wq, wk, wv, Qw, Kw, Vt);
    k_attn<<<dim3(512), 256, 0, stream>>>(Qw, Kw, Vt, AO, Linv);
    k_pw_o<<<dim3(2560), 256, 0, stream>>>(Qw, Kw, Linv, P, AO, wo, out);
}